// Round 3
// baseline (215.483 us; speedup 1.0000x reference)
//
#include <hip/hip_runtime.h>
#include <hip/hip_bf16.h>
#include <math.h>

// GAT forward, N=4096, nfeat=512, nhid=64, nheads=8, nout=56, f32 in/out.
// R18 = R17 with the WORKSPACE OVERLAP FIXED. R16/R17 both failed with
// identical absmax 0.982 — root cause was NOT the multiplicative softmax
// (algebra verified) but a 512-byte overlap: eb2L [23740416 + 32768 =
// 23773184) vs img2h placed at 23772672. mid's blocks race on those bytes
// -> corrupted layer-2 factors/image -> O(1) output error, deterministic.
// R18 moves img2h to 23773184 and WT_hi to 24297472. All kernels are
// byte-identical to R17:
//   (a) multiplicative softmax: w' = max(r_i*B_j, b_j)*adj, r=exp(.8 s1),
//       B=exp(s2), b=exp(.2 s2) per-row; zero transcendentals in attn loop.
//   den = f32 sum of the SAME bf16-rounded (half-up) weights (R15 path).
// Workspace ~24.82 MB.

#define GN 4096
#define GNH 8
#define LOG2E 1.4426950408889634f

typedef __bf16 bf16x8 __attribute__((ext_vector_type(8)));
typedef float f32x4 __attribute__((ext_vector_type(4)));

#if defined(__has_builtin)
#if __has_builtin(__builtin_amdgcn_exp2f)
#define FAST_EXP2(x) __builtin_amdgcn_exp2f(x)
#endif
#if __has_builtin(__builtin_amdgcn_perm)
#define FAST_PERM(a, b, s) __builtin_amdgcn_perm((a), (b), (s))
#endif
#endif
#ifndef FAST_EXP2
#define FAST_EXP2(x) __expf((x)*0.6931471805599453f)
#endif
#ifndef FAST_PERM
__device__ inline unsigned FAST_PERM(unsigned a, unsigned b, unsigned) {
    return (a & 0xFFFF0000u) | (b >> 16);
}
#endif

// round-half-up hi only, packed pair: low 16 = v0's bf16, high 16 = v1's
__device__ inline unsigned hi_pack2(float w0, float w1) {
    unsigned u0 = __float_as_uint(w0) + 0x8000u;
    unsigned u1 = __float_as_uint(w1) + 0x8000u;
    return FAST_PERM(u1, u0, 0x07060302u);
}

// Fused prep:
//  [0,16384)      pack_adj  (bitmask)
//  [16384,17408)  conv_x    -> swizzled x image (hi only), tiles [itile*8+kt]
//  [17408,17472)  conv_wt   -> swizzled W^T image (hi only), tiles [head*8+kt]
// Image unit (m, c) at shorts offset m*64 + ((c^(m&7))*8), elems k = c*8+q.
__global__ __launch_bounds__(256) void prep(const int* __restrict__ adj,
                                            const float* __restrict__ x,
                                            const float* __restrict__ Ws,
                                            unsigned long long* __restrict__ adjb,
                                            unsigned short* __restrict__ xh,
                                            unsigned short* __restrict__ wth) {
    const int b = blockIdx.x;
    const int tid = threadIdx.x;
    if (b < 16384) {
        const int wv = tid >> 6, lane = tid & 63;
        const size_t ebase = ((size_t)b * 4 + wv) * 256;
        unsigned long long m[4];
        #pragma unroll
        for (int e = 0; e < 4; ++e)
            m[e] = __ballot(adj[ebase + e * 64 + lane] > 0);
        if (lane == 0) {
            #pragma unroll
            for (int e = 0; e < 4; ++e) adjb[(ebase >> 6) + e] = m[e];
        }
    } else if (b < 17408) {
        int gid = (b - 16384) * 256 + tid;           // over 4096 rows x 64 units
        int i = gid >> 6, c64 = gid & 63;
        const float* xp = x + (size_t)i * 512 + c64 * 8;
        float4 a = *(const float4*)xp;
        float4 v = *(const float4*)(xp + 4);
        unsigned hp[4];
        hp[0] = hi_pack2(a.x, a.y);
        hp[1] = hi_pack2(a.z, a.w);
        hp[2] = hi_pack2(v.x, v.y);
        hp[3] = hi_pack2(v.z, v.w);
        int il = i & 63, kt = c64 >> 3, c = c64 & 7;
        size_t base = ((size_t)(i >> 6) * 8 + kt) * 4096 + il * 64 + ((c ^ (il & 7)) * 8);
        *(uint4*)&xh[base] = *(uint4*)hp;
    } else {
        __shared__ float t[64][65];
        int b2 = b - 17408;                          // head*8 + kt
        int head = b2 >> 3, k0 = (b2 & 7) * 64;
        #pragma unroll
        for (int it = 0; it < 4; ++it) {
            int e = (tid + it * 256) * 4;            // over 64k x 64f
            int kl = e >> 6, f4 = e & 63;
            float4 v = *(const float4*)&Ws[((size_t)head * 512 + k0 + kl) * 64 + f4];
            t[f4 + 0][kl] = v.x; t[f4 + 1][kl] = v.y;
            t[f4 + 2][kl] = v.z; t[f4 + 3][kl] = v.w;
        }
        __syncthreads();
        int f = tid >> 2;
        #pragma unroll
        for (int p = 0; p < 2; ++p) {
            int c = (tid & 3) * 2 + p;
            unsigned hp[4];
            #pragma unroll
            for (int pp = 0; pp < 4; ++pp)
                hp[pp] = hi_pack2(t[f][c * 8 + 2 * pp], t[f][c * 8 + 2 * pp + 1]);
            size_t base = (size_t)b2 * 4096 + f * 64 + ((c ^ (f & 7)) * 8);
            *(uint4*)&wth[base] = *(uint4*)hp;
        }
    }
}

// h = x_hi @ W_hi (single bf16 product), m97-style staging, 4 blk/CU.
// Epilogue emits hi-only swizzled h image + per-row softmax factors:
// rL = exp(.8*s1), ebL = {exp(s2), exp(.2*s2)}. grid (8 heads, 64 itiles).
__global__ __launch_bounds__(256) void gemm_fused(const unsigned short* __restrict__ xh,
                                                  const unsigned short* __restrict__ wth,
                                                  const float* __restrict__ As,
                                                  unsigned short* __restrict__ imgh,
                                                  float* __restrict__ rL,
                                                  float2* __restrict__ ebL) {
    __shared__ __align__(16) unsigned short lds[2][2][4096];  // 32 KB: [buf][x,w]
    const int tid = threadIdx.x;
    const int head = blockIdx.x;
    const int itile = blockIdx.y;
    const int i0 = itile * 64;
    const unsigned short* srcs[2] = {xh + (size_t)itile * 8 * 4096,
                                     wth + (size_t)head * 8 * 4096};
    const int lane = tid & 63, wv_ = tid >> 6;
    const int mi = (wv_ & 1) * 32, fi = (wv_ >> 1) * 32;
    const int row = lane & 15, quad = lane >> 4;
    f32x4 acc[2][2] = {};

    #define GSTAGE(buf, kt)                                                                \
        do {                                                                               \
            _Pragma("unroll")                                                              \
            for (int q_ = 0; q_ < 2; ++q_) {                                               \
                const unsigned short* s_ = srcs[q_] + (size_t)(kt) * 4096;                 \
                _Pragma("unroll")                                                          \
                for (int c_ = 0; c_ < 2; ++c_)                                             \
                    __builtin_amdgcn_global_load_lds(                                      \
                        (const __attribute__((address_space(1))) unsigned int*)(s_ + c_ * 2048 + tid * 8), \
                        (__attribute__((address_space(3))) unsigned int*)&lds[buf][q_][c_ * 2048 + tid * 8], \
                        16, 0, 0);                                                         \
            }                                                                              \
        } while (0)

    GSTAGE(0, 0);
    for (int kt = 0; kt < 8; ++kt) {
        __syncthreads();                             // drains loads into buf cur
        const int cur = kt & 1;
        if (kt + 1 < 8) GSTAGE(cur ^ 1, kt + 1);
        #pragma unroll
        for (int ks = 0; ks < 2; ++ks) {
            bf16x8 ah[2], bh[2];
            #pragma unroll
            for (int t = 0; t < 2; ++t) {
                const int m_ = mi + t * 16 + row;
                const int offa = m_ * 64 + (((ks * 4 + quad) ^ (m_ & 7)) * 8);
                ah[t] = *(const bf16x8*)&lds[cur][0][offa];
                const int f_ = fi + t * 16 + row;
                const int offb = f_ * 64 + (((ks * 4 + quad) ^ (f_ & 7)) * 8);
                bh[t] = *(const bf16x8*)&lds[cur][1][offb];
            }
            #pragma unroll
            for (int mt = 0; mt < 2; ++mt)
                #pragma unroll
                for (int nt = 0; nt < 2; ++nt)
                    acc[mt][nt] = __builtin_amdgcn_mfma_f32_16x16x32_bf16(ah[mt], bh[nt], acc[mt][nt], 0, 0, 0);
        }
    }
    #undef GSTAGE
    // ---- fused epilogue ----
    __syncthreads();
    float* ht = (float*)&lds[0][0][0];               // 64 x 68 f32 (17.4 KB <= 32 KB)
    #pragma unroll
    for (int mt = 0; mt < 2; ++mt)
        #pragma unroll
        for (int nt = 0; nt < 2; ++nt)
            #pragma unroll
            for (int r = 0; r < 4; ++r)
                ht[(mi + mt * 16 + quad * 4 + r) * 68 + fi + nt * 16 + row] = acc[mt][nt][r];
    __syncthreads();
    {   // s1/s2 -> row factors: thread t -> row t>>2, seg (t&3)*16
        const int rrow = tid >> 2, seg = (tid & 3) * 16;
        const float* ah = As + head * 128;
        float p1 = 0.f, p2 = 0.f;
        #pragma unroll
        for (int c = 0; c < 16; ++c) {
            float v = ht[rrow * 68 + seg + c];
            p1 += v * ah[seg + c];
            p2 += v * ah[64 + seg + c];
        }
        p1 += __shfl_xor(p1, 1); p1 += __shfl_xor(p1, 2);
        p2 += __shfl_xor(p2, 1); p2 += __shfl_xor(p2, 2);
        if ((tid & 3) == 0) {
            const int gi = i0 + rrow;
            rL[head * GN + gi] = FAST_EXP2(0.8f * p1 * LOG2E);
            float2 e;
            e.x = FAST_EXP2(p2 * LOG2E);
            e.y = FAST_EXP2(0.2f * p2 * LOG2E);
            ebL[head * GN + gi] = e;
        }
    }
    {   // swizzled image emit (hi only)
        const int f = tid >> 2;
        size_t base = ((size_t)head * 64 + itile) * 4096 + (size_t)f * 64;
        #pragma unroll
        for (int p = 0; p < 2; ++p) {
            int c = (tid & 3) * 2 + p;
            unsigned hp[4];
            #pragma unroll
            for (int pp = 0; pp < 4; ++pp)
                hp[pp] = hi_pack2(ht[(c * 8 + 2 * pp) * 68 + f], ht[(c * 8 + 2 * pp + 1) * 68 + f]);
            int off = (c ^ (f & 7)) * 8;
            *(uint4*)&imgh[base + off] = *(uint4*)hp;
        }
    }
}

// Fused masked-softmax attention, MULTIPLICATIVE weights, R15 den:
// w'_ij = max(r_i*B_j, b_j) * adj  -- no transcendentals in the loop.
// Weights rounded to bf16-hi (half-up) exactly as R15; den is the f32 sum
// of the SAME rounded values (per-lane sum, shfl_xor 16/32, lane<16 write).
// 256 thr = 4 waves x 16 rows, nt=4. eb/adj loads issued BEFORE STAGE(next)
// (vmcnt decoupling). grid (64 i-tiles, GNH*NCHUNK or NCHUNK).
template <int NCHUNK>
__global__ __launch_bounds__(256, 4) void attn10(const unsigned short* __restrict__ imgh,
                                                 const float* __restrict__ rg,
                                                 const float2* __restrict__ ebg,
                                                 const unsigned long long* __restrict__ adjb,
                                                 float* __restrict__ pO,
                                                 float* __restrict__ pd) {
    __shared__ __align__(16) unsigned short hb[2][4096];   // [buf][hi, swizzled 64x64]
    const int tid = threadIdx.x;
    const int lane = tid & 63, wv = tid >> 6;
    const int row = lane & 15, quad = lane >> 4;
    const int head = blockIdx.y / NCHUNK;
    const int chunk = blockIdx.y % NCHUNK;
    const int i0 = blockIdx.x * 64;
    const int jb = chunk * (GN / NCHUNK);
    const int njt = (GN / NCHUNK) / 64;
    const int jt0 = jb >> 6;
    const unsigned short* ih = imgh + (size_t)head * (64 * GN);
    const float2* ebh = ebg + (size_t)head * GN;
    const int gr = i0 + wv * 16 + row;
    const float rv = rg[head * GN + gr];
    const unsigned long long* adjr = adjb + (size_t)gr * 64 + jt0;

    f32x4 acc[4] = {};
    float den = 0.f;

    #define STAGE(buf, T)                                                                  \
        do {                                                                               \
            const unsigned short* gh_ = ih + (size_t)(T) * 4096;                           \
            _Pragma("unroll")                                                              \
            for (int c_ = 0; c_ < 2; ++c_)                                                 \
                __builtin_amdgcn_global_load_lds(                                          \
                    (const __attribute__((address_space(1))) unsigned int*)(gh_ + c_ * 2048 + tid * 8), \
                    (__attribute__((address_space(3))) unsigned int*)&hb[buf][c_ * 2048 + tid * 8],     \
                    16, 0, 0);                                                             \
        } while (0)

    STAGE(0, jt0);
    for (int jt = 0; jt < njt; ++jt) {
        __syncthreads();                             // drains loads into buf cur
        const int cur = jt & 1;
        const int j0 = jb + jt * 64;
        // ---- loads for the CURRENT tile, issued BEFORE next-tile staging ----
        const unsigned long long wd = adjr[jt];
        const float4* ep0 = (const float4*)(ebh + j0 + quad * 8);        // j: +0..7
        const float4* ep1 = (const float4*)(ebh + j0 + 32 + quad * 8);   // j: +32..39
        const float4 f00 = ep0[0], f01 = ep0[1], f02 = ep0[2], f03 = ep0[3];
        const float4 f10 = ep1[0], f11 = ep1[1], f12 = ep1[2], f13 = ep1[3];
        // ---- next-tile staging: newest in vmcnt queue, NOT drained by eb waits
        if (jt + 1 < njt) STAGE(cur ^ 1, jt0 + jt + 1);
        #pragma unroll
        for (int ks = 0; ks < 2; ++ks) {
            const int kb = ks * 32 + quad * 8;
            const unsigned bits = (unsigned)(wd >> kb) & 0xFFu;
            const float4 e4[4] = {ks ? f10 : f00, ks ? f11 : f01,
                                  ks ? f12 : f02, ks ? f13 : f03};
            union { unsigned u[4]; bf16x8 v; } hfr;
            #pragma unroll
            for (int p = 0; p < 4; ++p) {
                const float4 e = e4[p];              // {B0, b0, B1, b1}
                const float m0 = (float)((bits >> (2 * p)) & 1u);
                const float m1 = (float)((bits >> (2 * p + 1)) & 1u);
                const float w0 = fmaxf(rv * e.x, e.y) * m0;
                const float w1 = fmaxf(rv * e.z, e.w) * m1;
                unsigned u0 = __float_as_uint(w0) + 0x8000u;
                unsigned u1 = __float_as_uint(w1) + 0x8000u;
                // denominator from the SAME rounded values the MFMA consumes
                den += __uint_as_float(u0 & 0xFFFF0000u) + __uint_as_float(u1 & 0xFFFF0000u);
                hfr.u[p] = FAST_PERM(u1, u0, 0x07060302u);
            }
            #pragma unroll
            for (int nt = 0; nt < 4; ++nt) {
                const int f = nt * 16 + row;
                const int off = f * 64 + (((ks * 4 + quad) ^ (f & 7)) * 8);
                bf16x8 bh = *(const bf16x8*)&hb[cur][off];
                acc[nt] = __builtin_amdgcn_mfma_f32_16x16x32_bf16(hfr.v, bh, acc[nt], 0, 0, 0);
            }
        }
    }
    #undef STAGE
    den += __shfl_xor(den, 16);
    den += __shfl_xor(den, 32);
    float* o = pO + (size_t)blockIdx.y * (GN * 64);
    #pragma unroll
    for (int r = 0; r < 4; ++r) {
        const int grow = i0 + wv * 16 + quad * 4 + r;
        #pragma unroll
        for (int nt = 0; nt < 4; ++nt)
            o[(size_t)grow * 64 + nt * 16 + row] = acc[nt][r];
    }
    if (lane < 16) pd[blockIdx.y * GN + i0 + wv * 16 + lane] = den;
}

// Fused zred + l2prep, 16 rows/block (256 blocks): combine 2-chunk L1
// partials -> z (LDS) -> h2 = z @ W_out -> row factors + hi-only image.
__global__ __launch_bounds__(256) void mid(const float* __restrict__ pO,
                                           const float* __restrict__ pd,
                                           const float* __restrict__ Wo,
                                           const float* __restrict__ ao,
                                           unsigned short* __restrict__ img2h,
                                           float* __restrict__ rbL,
                                           float2* __restrict__ eb2L) {
    __shared__ __align__(16) float zt[16][68];
    __shared__ float Wl[64 * 57];
    __shared__ float invd[8][16];
    const int tid = threadIdx.x;
    const int i0 = blockIdx.x * 16;
    for (int idx = tid; idx < 64 * 56; idx += 256) {
        int k = idx / 56, c = idx - k * 56;
        Wl[k * 57 + c] = Wo[idx];
    }
    if (tid < 128) {
        int hd = tid >> 4, r = tid & 15;
        invd[hd][r] = 1.f / (pd[(2 * hd) * GN + i0 + r] + pd[(2 * hd + 1) * GN + i0 + r]);
    }
    __syncthreads();
    #pragma unroll
    for (int it = 0; it < 4; ++it) {                 // z fill: 16x64 elems
        int e = it * 256 + tid;
        int r = e >> 6, f = e & 63;
        size_t base = (size_t)(i0 + r) * 64 + f;
        float s = 0.f;
        #pragma unroll
        for (int hd = 0; hd < GNH; ++hd) {
            float o = pO[(size_t)(2 * hd) * (GN * 64) + base] +
                      pO[(size_t)(2 * hd + 1) * (GN * 64) + base];
            float v = o * invd[hd][r];
            s += v > 0.f ? v : FAST_EXP2(v * LOG2E) - 1.f;
        }
        zt[r][f] = s * 0.125f;
    }
    __syncthreads();
    const int rrow = tid >> 4, cseg = (tid & 15) * 4;
    float hreg[4] = {0.f, 0.f, 0.f, 0.f};
    for (int k0 = 0; k0 < 64; k0 += 4) {
        float4 zv = *(const float4*)&zt[rrow][k0];
        #pragma unroll
        for (int c = 0; c < 4; ++c) {
            int col = cseg + c;
            if (col < 56)
                hreg[c] += zv.x * Wl[k0 * 57 + col] + zv.y * Wl[(k0 + 1) * 57 + col] +
                           zv.z * Wl[(k0 + 2) * 57 + col] + zv.w * Wl[(k0 + 3) * 57 + col];
        }
    }
    {   // row factors for L2 attention
        float p1 = 0.f, p2 = 0.f;
        #pragma unroll
        for (int c = 0; c < 4; ++c) {
            int col = cseg + c;
            if (col < 56) {
                p1 += hreg[c] * ao[col];
                p2 += hreg[c] * ao[56 + col];
            }
        }
        p1 += __shfl_xor(p1, 1); p1 += __shfl_xor(p1, 2);
        p1 += __shfl_xor(p1, 4); p1 += __shfl_xor(p1, 8);
        p2 += __shfl_xor(p2, 1); p2 += __shfl_xor(p2, 2);
        p2 += __shfl_xor(p2, 4); p2 += __shfl_xor(p2, 8);
        if ((tid & 15) == 0) {
            rbL[i0 + rrow] = FAST_EXP2(0.8f * p1 * LOG2E);
            float2 e;
            e.x = FAST_EXP2(p2 * LOG2E);
            e.y = FAST_EXP2(0.2f * p2 * LOG2E);
            eb2L[i0 + rrow] = e;
        }
    }
    __syncthreads();
    #pragma unroll
    for (int c = 0; c < 4; ++c) zt[rrow][cseg + c] = (cseg + c < 56) ? hreg[c] : 0.f;
    __syncthreads();
    if (tid < 128) {                                 // img emit: 64 f x 2 c-units
        const int jt = i0 >> 6;
        const int cbase = (i0 & 63) >> 3;
        const int f = tid >> 1, c = cbase + (tid & 1);
        const int lr = (tid & 1) * 8;
        unsigned hp[4];
        #pragma unroll
        for (int pp = 0; pp < 4; ++pp)
            hp[pp] = hi_pack2(zt[lr + 2 * pp][f], zt[lr + 2 * pp + 1][f]);
        size_t base = (size_t)jt * 4096 + f * 64 + ((c ^ (f & 7)) * 8);
        *(uint4*)&img2h[base] = *(uint4*)hp;
    }
}

// combine 16 j-chunk partials, /denom, elu, softmax(56) -> out
__global__ __launch_bounds__(256) void fink2(const float* __restrict__ pO,
                                             const float* __restrict__ pd,
                                             float* __restrict__ out) {
    const int lane = threadIdx.x & 63;
    const int w = threadIdx.x >> 6;
    const int i = blockIdx.x * 4 + w;
    float o = 0.f, d = 0.f;
    #pragma unroll
    for (int c = 0; c < 16; ++c) d += pd[c * GN + i];
    if (lane < 56) {
        #pragma unroll
        for (int c = 0; c < 16; ++c) o += pO[(size_t)c * (GN * 64) + (size_t)i * 64 + lane];
    }
    float v = -1e30f;
    if (lane < 56) {
        float t = o / d;
        v = t > 0.f ? t : expm1f(t);
    }
    float m = v;
    #pragma unroll
    for (int off = 32; off; off >>= 1) m = fmaxf(m, __shfl_down(m, off));
    m = __shfl(m, 0);
    float p = (lane < 56) ? __expf(v - m) : 0.f;
    float s = p;
    #pragma unroll
    for (int off = 32; off; off >>= 1) s += __shfl_down(s, off);
    s = __shfl(s, 0);
    if (lane < 56) out[(size_t)i * 56 + lane] = p / s;
}

extern "C" void kernel_launch(void* const* d_in, const int* in_sizes, int n_in,
                              void* d_out, int out_size, void* d_ws, size_t ws_size,
                              hipStream_t stream) {
    const float* x    = (const float*)d_in[0];
    const int*   adj  = (const int*)d_in[1];
    const float* Ws   = (const float*)d_in[2];
    const float* As   = (const float*)d_in[3];
    const float* Wo   = (const float*)d_in[4];
    const float* ao   = (const float*)d_in[5];
    float* out = (float*)d_out;

    char* ws = (char*)d_ws;
    unsigned long long* adjb = (unsigned long long*)(ws + 0);           // [0, 2097152)
    unsigned short* img1h = (unsigned short*)(ws + 2097152);            // [2097152, 6291456)
    float* pO    = (float*)(ws + 6291456);                              // [6291456, 23068672) 16 slices
    unsigned short* x_hi = (unsigned short*)(ws + 6291456);             // alias pO (pre-gemm only)
    float* pd    = (float*)(ws + 23068672);                             // [23068672, 23330816)
    float* rL    = (float*)(ws + 23330816);                             // [23330816, 23461888)
    float2* ebL  = (float2*)(ws + 23461888);                            // [23461888, 23724032)
    float* rbL   = (float*)(ws + 23724032);                             // [23724032, 23740416)
    float2* eb2L = (float2*)(ws + 23740416);                            // [23740416, 23773184)
    unsigned short* img2h = (unsigned short*)(ws + 23773184);           // [23773184, 24297472)
    unsigned short* WT_hi = (unsigned short*)(ws + 24297472);           // [24297472, 24821760)
    // total ~24.82 MB, no overlaps (R16/R17 had eb2L/img2h colliding by 512 B)

    prep<<<17472, 256, 0, stream>>>(adj, x, Ws, adjb, x_hi, WT_hi);
    gemm_fused<<<dim3(8, 64), 256, 0, stream>>>(x_hi, WT_hi, As, img1h, rL, ebL);
    attn10<2><<<dim3(64, 16), 256, 0, stream>>>(img1h, rL, ebL, adjb, pO, pd);
    mid<<<256, 256, 0, stream>>>(pO, pd, Wo, ao, img2h, rbL, eb2L);
    attn10<16><<<dim3(64, 16), 256, 0, stream>>>(img2h, rbL, eb2L, adjb, pO, pd);
    fink2<<<1024, 256, 0, stream>>>(pO, pd, out);
}

// Round 4
// 207.326 us; speedup vs baseline: 1.0393x; 1.0393x over previous
//
#include <hip/hip_runtime.h>
#include <hip/hip_bf16.h>
#include <math.h>

// GAT forward, N=4096, nfeat=512, nhid=64, nheads=8, nout=56, f32 in/out.
// R19 vs R18 (R18: 215.5us PASS; attn10 72.8us with VALUBusy 50% -- the
// multiplicative softmax cut VALU work 43.8->36.4us but DOUBLED the scalar
// eb load bytes (8x float4 vs 4x), adding ~15us/dispatch of L2-latency
// stall at each tile top that the thinner VALU work no longer hides):
//  - attn10: PREFETCH eb/adj for tile jt+1 into named registers during
//    tile jt compute (issued after STAGE(next)). The barrier's vmcnt(0)
//    drain guarantees readiness -> zero steady-state scalar-load stall.
//    Zero numerics change.
//  - den via ones-column MFMA, RE-LANDED: R16/R17 bisect proved the 0.98
//    failure was the eb2L/img2h 512B workspace overlap (fixed in R18), NOT
//    this. A-operand = same wfr the proven PV MFMA eats; B=ones is layout-
//    independent; C/D mapping (col=lane&15,row=quad*4+reg) => row==0 lanes
//    write rows quad*4+r. Removes 4 VALU/pair + shfl reduce; MFMA pipe was
//    90% idle.
//  prep / gemm_fused / mid / fink2 byte-identical to R18. Workspace same.

#define GN 4096
#define GNH 8
#define LOG2E 1.4426950408889634f

typedef __bf16 bf16x8 __attribute__((ext_vector_type(8)));
typedef float f32x4 __attribute__((ext_vector_type(4)));

#if defined(__has_builtin)
#if __has_builtin(__builtin_amdgcn_exp2f)
#define FAST_EXP2(x) __builtin_amdgcn_exp2f(x)
#endif
#if __has_builtin(__builtin_amdgcn_perm)
#define FAST_PERM(a, b, s) __builtin_amdgcn_perm((a), (b), (s))
#endif
#endif
#ifndef FAST_EXP2
#define FAST_EXP2(x) __expf((x)*0.6931471805599453f)
#endif
#ifndef FAST_PERM
__device__ inline unsigned FAST_PERM(unsigned a, unsigned b, unsigned) {
    return (a & 0xFFFF0000u) | (b >> 16);
}
#endif

// round-half-up hi only, packed pair: low 16 = v0's bf16, high 16 = v1's
__device__ inline unsigned hi_pack2(float w0, float w1) {
    unsigned u0 = __float_as_uint(w0) + 0x8000u;
    unsigned u1 = __float_as_uint(w1) + 0x8000u;
    return FAST_PERM(u1, u0, 0x07060302u);
}

// Fused prep:
//  [0,16384)      pack_adj  (bitmask)
//  [16384,17408)  conv_x    -> swizzled x image (hi only), tiles [itile*8+kt]
//  [17408,17472)  conv_wt   -> swizzled W^T image (hi only), tiles [head*8+kt]
// Image unit (m, c) at shorts offset m*64 + ((c^(m&7))*8), elems k = c*8+q.
__global__ __launch_bounds__(256) void prep(const int* __restrict__ adj,
                                            const float* __restrict__ x,
                                            const float* __restrict__ Ws,
                                            unsigned long long* __restrict__ adjb,
                                            unsigned short* __restrict__ xh,
                                            unsigned short* __restrict__ wth) {
    const int b = blockIdx.x;
    const int tid = threadIdx.x;
    if (b < 16384) {
        const int wv = tid >> 6, lane = tid & 63;
        const size_t ebase = ((size_t)b * 4 + wv) * 256;
        unsigned long long m[4];
        #pragma unroll
        for (int e = 0; e < 4; ++e)
            m[e] = __ballot(adj[ebase + e * 64 + lane] > 0);
        if (lane == 0) {
            #pragma unroll
            for (int e = 0; e < 4; ++e) adjb[(ebase >> 6) + e] = m[e];
        }
    } else if (b < 17408) {
        int gid = (b - 16384) * 256 + tid;           // over 4096 rows x 64 units
        int i = gid >> 6, c64 = gid & 63;
        const float* xp = x + (size_t)i * 512 + c64 * 8;
        float4 a = *(const float4*)xp;
        float4 v = *(const float4*)(xp + 4);
        unsigned hp[4];
        hp[0] = hi_pack2(a.x, a.y);
        hp[1] = hi_pack2(a.z, a.w);
        hp[2] = hi_pack2(v.x, v.y);
        hp[3] = hi_pack2(v.z, v.w);
        int il = i & 63, kt = c64 >> 3, c = c64 & 7;
        size_t base = ((size_t)(i >> 6) * 8 + kt) * 4096 + il * 64 + ((c ^ (il & 7)) * 8);
        *(uint4*)&xh[base] = *(uint4*)hp;
    } else {
        __shared__ float t[64][65];
        int b2 = b - 17408;                          // head*8 + kt
        int head = b2 >> 3, k0 = (b2 & 7) * 64;
        #pragma unroll
        for (int it = 0; it < 4; ++it) {
            int e = (tid + it * 256) * 4;            // over 64k x 64f
            int kl = e >> 6, f4 = e & 63;
            float4 v = *(const float4*)&Ws[((size_t)head * 512 + k0 + kl) * 64 + f4];
            t[f4 + 0][kl] = v.x; t[f4 + 1][kl] = v.y;
            t[f4 + 2][kl] = v.z; t[f4 + 3][kl] = v.w;
        }
        __syncthreads();
        int f = tid >> 2;
        #pragma unroll
        for (int p = 0; p < 2; ++p) {
            int c = (tid & 3) * 2 + p;
            unsigned hp[4];
            #pragma unroll
            for (int pp = 0; pp < 4; ++pp)
                hp[pp] = hi_pack2(t[f][c * 8 + 2 * pp], t[f][c * 8 + 2 * pp + 1]);
            size_t base = (size_t)b2 * 4096 + f * 64 + ((c ^ (f & 7)) * 8);
            *(uint4*)&wth[base] = *(uint4*)hp;
        }
    }
}

// h = x_hi @ W_hi (single bf16 product), m97-style staging, 4 blk/CU.
// Epilogue emits hi-only swizzled h image + per-row softmax factors:
// rL = exp(.8*s1), ebL = {exp(s2), exp(.2*s2)}. grid (8 heads, 64 itiles).
__global__ __launch_bounds__(256) void gemm_fused(const unsigned short* __restrict__ xh,
                                                  const unsigned short* __restrict__ wth,
                                                  const float* __restrict__ As,
                                                  unsigned short* __restrict__ imgh,
                                                  float* __restrict__ rL,
                                                  float2* __restrict__ ebL) {
    __shared__ __align__(16) unsigned short lds[2][2][4096];  // 32 KB: [buf][x,w]
    const int tid = threadIdx.x;
    const int head = blockIdx.x;
    const int itile = blockIdx.y;
    const int i0 = itile * 64;
    const unsigned short* srcs[2] = {xh + (size_t)itile * 8 * 4096,
                                     wth + (size_t)head * 8 * 4096};
    const int lane = tid & 63, wv_ = tid >> 6;
    const int mi = (wv_ & 1) * 32, fi = (wv_ >> 1) * 32;
    const int row = lane & 15, quad = lane >> 4;
    f32x4 acc[2][2] = {};

    #define GSTAGE(buf, kt)                                                                \
        do {                                                                               \
            _Pragma("unroll")                                                              \
            for (int q_ = 0; q_ < 2; ++q_) {                                               \
                const unsigned short* s_ = srcs[q_] + (size_t)(kt) * 4096;                 \
                _Pragma("unroll")                                                          \
                for (int c_ = 0; c_ < 2; ++c_)                                             \
                    __builtin_amdgcn_global_load_lds(                                      \
                        (const __attribute__((address_space(1))) unsigned int*)(s_ + c_ * 2048 + tid * 8), \
                        (__attribute__((address_space(3))) unsigned int*)&lds[buf][q_][c_ * 2048 + tid * 8], \
                        16, 0, 0);                                                         \
            }                                                                              \
        } while (0)

    GSTAGE(0, 0);
    for (int kt = 0; kt < 8; ++kt) {
        __syncthreads();                             // drains loads into buf cur
        const int cur = kt & 1;
        if (kt + 1 < 8) GSTAGE(cur ^ 1, kt + 1);
        #pragma unroll
        for (int ks = 0; ks < 2; ++ks) {
            bf16x8 ah[2], bh[2];
            #pragma unroll
            for (int t = 0; t < 2; ++t) {
                const int m_ = mi + t * 16 + row;
                const int offa = m_ * 64 + (((ks * 4 + quad) ^ (m_ & 7)) * 8);
                ah[t] = *(const bf16x8*)&lds[cur][0][offa];
                const int f_ = fi + t * 16 + row;
                const int offb = f_ * 64 + (((ks * 4 + quad) ^ (f_ & 7)) * 8);
                bh[t] = *(const bf16x8*)&lds[cur][1][offb];
            }
            #pragma unroll
            for (int mt = 0; mt < 2; ++mt)
                #pragma unroll
                for (int nt = 0; nt < 2; ++nt)
                    acc[mt][nt] = __builtin_amdgcn_mfma_f32_16x16x32_bf16(ah[mt], bh[nt], acc[mt][nt], 0, 0, 0);
        }
    }
    #undef GSTAGE
    // ---- fused epilogue ----
    __syncthreads();
    float* ht = (float*)&lds[0][0][0];               // 64 x 68 f32 (17.4 KB <= 32 KB)
    #pragma unroll
    for (int mt = 0; mt < 2; ++mt)
        #pragma unroll
        for (int nt = 0; nt < 2; ++nt)
            #pragma unroll
            for (int r = 0; r < 4; ++r)
                ht[(mi + mt * 16 + quad * 4 + r) * 68 + fi + nt * 16 + row] = acc[mt][nt][r];
    __syncthreads();
    {   // s1/s2 -> row factors: thread t -> row t>>2, seg (t&3)*16
        const int rrow = tid >> 2, seg = (tid & 3) * 16;
        const float* ah = As + head * 128;
        float p1 = 0.f, p2 = 0.f;
        #pragma unroll
        for (int c = 0; c < 16; ++c) {
            float v = ht[rrow * 68 + seg + c];
            p1 += v * ah[seg + c];
            p2 += v * ah[64 + seg + c];
        }
        p1 += __shfl_xor(p1, 1); p1 += __shfl_xor(p1, 2);
        p2 += __shfl_xor(p2, 1); p2 += __shfl_xor(p2, 2);
        if ((tid & 3) == 0) {
            const int gi = i0 + rrow;
            rL[head * GN + gi] = FAST_EXP2(0.8f * p1 * LOG2E);
            float2 e;
            e.x = FAST_EXP2(p2 * LOG2E);
            e.y = FAST_EXP2(0.2f * p2 * LOG2E);
            ebL[head * GN + gi] = e;
        }
    }
    {   // swizzled image emit (hi only)
        const int f = tid >> 2;
        size_t base = ((size_t)head * 64 + itile) * 4096 + (size_t)f * 64;
        #pragma unroll
        for (int p = 0; p < 2; ++p) {
            int c = (tid & 3) * 2 + p;
            unsigned hp[4];
            #pragma unroll
            for (int pp = 0; pp < 4; ++pp)
                hp[pp] = hi_pack2(ht[(c * 8 + 2 * pp) * 68 + f], ht[(c * 8 + 2 * pp + 1) * 68 + f]);
            int off = (c ^ (f & 7)) * 8;
            *(uint4*)&imgh[base + off] = *(uint4*)hp;
        }
    }
}

// Fused masked-softmax attention, MULTIPLICATIVE weights:
// w'_ij = max(r_i*B_j, b_j) * adj  -- no transcendentals in the loop.
// R19: eb/adj for tile jt+1 PREFETCHED into registers during tile jt
// (issued after STAGE(next); barrier vmcnt(0) drain guarantees readiness).
// den = ones-column MFMA on the SAME rounded bf16 weights the PV MFMA
// consumes (D[i][*] = sum_k w[i][k]; row==0 lanes write rows quad*4+r).
// 256 thr = 4 waves x 16 rows, nt=4. grid (64 i-tiles, GNH*NCHUNK or NCHUNK).
template <int NCHUNK>
__global__ __launch_bounds__(256, 4) void attn10(const unsigned short* __restrict__ imgh,
                                                 const float* __restrict__ rg,
                                                 const float2* __restrict__ ebg,
                                                 const unsigned long long* __restrict__ adjb,
                                                 float* __restrict__ pO,
                                                 float* __restrict__ pd) {
    __shared__ __align__(16) unsigned short hb[2][4096];   // [buf][hi, swizzled 64x64]
    const int tid = threadIdx.x;
    const int lane = tid & 63, wv = tid >> 6;
    const int row = lane & 15, quad = lane >> 4;
    const int head = blockIdx.y / NCHUNK;
    const int chunk = blockIdx.y % NCHUNK;
    const int i0 = blockIdx.x * 64;
    const int jb = chunk * (GN / NCHUNK);
    const int njt = (GN / NCHUNK) / 64;
    const int jt0 = jb >> 6;
    const unsigned short* ih = imgh + (size_t)head * (64 * GN);
    const float2* ebh = ebg + (size_t)head * GN;
    const int gr = i0 + wv * 16 + row;
    const float rv = rg[head * GN + gr];
    const unsigned long long* adjr = adjb + (size_t)gr * 64 + jt0;

    f32x4 acc[4] = {};
    f32x4 accd = {};
    union { unsigned u[4]; bf16x8 v; } ones;
    #pragma unroll
    for (int q = 0; q < 4; ++q) ones.u[q] = 0x3F803F80u;   // bf16 1.0 x8

    #define STAGE(buf, T)                                                                  \
        do {                                                                               \
            const unsigned short* gh_ = ih + (size_t)(T) * 4096;                           \
            _Pragma("unroll")                                                              \
            for (int c_ = 0; c_ < 2; ++c_)                                                 \
                __builtin_amdgcn_global_load_lds(                                          \
                    (const __attribute__((address_space(1))) unsigned int*)(gh_ + c_ * 2048 + tid * 8), \
                    (__attribute__((address_space(3))) unsigned int*)&hb[buf][c_ * 2048 + tid * 8],     \
                    16, 0, 0);                                                             \
        } while (0)

    STAGE(0, jt0);
    // ---- prologue prefetch of tile 0 scalars (covered by first barrier) ----
    const float2* ebp = ebh + jb + quad * 8;
    unsigned long long wdn = adjr[0];
    float4 n00 = *(const float4*)(ebp + 0);
    float4 n01 = *(const float4*)(ebp + 2);
    float4 n02 = *(const float4*)(ebp + 4);
    float4 n03 = *(const float4*)(ebp + 6);
    float4 n10 = *(const float4*)(ebp + 32);
    float4 n11 = *(const float4*)(ebp + 34);
    float4 n12 = *(const float4*)(ebp + 36);
    float4 n13 = *(const float4*)(ebp + 38);

    for (int jt = 0; jt < njt; ++jt) {
        __syncthreads();                             // drains loads into buf cur
        const int cur = jt & 1;
        // retire prefetched scalars for THIS tile
        const unsigned long long wd = wdn;
        const float4 f00 = n00, f01 = n01, f02 = n02, f03 = n03;
        const float4 f10 = n10, f11 = n11, f12 = n12, f13 = n13;
        if (jt + 1 < njt) {
            STAGE(cur ^ 1, jt0 + jt + 1);
            // prefetch NEXT tile scalars; consumed only after next barrier
            wdn = adjr[jt + 1];
            const float2* ebn = ebp + (jt + 1) * 64;
            n00 = *(const float4*)(ebn + 0);
            n01 = *(const float4*)(ebn + 2);
            n02 = *(const float4*)(ebn + 4);
            n03 = *(const float4*)(ebn + 6);
            n10 = *(const float4*)(ebn + 32);
            n11 = *(const float4*)(ebn + 34);
            n12 = *(const float4*)(ebn + 36);
            n13 = *(const float4*)(ebn + 38);
        }
        #pragma unroll
        for (int ks = 0; ks < 2; ++ks) {
            const int kb = ks * 32 + quad * 8;
            const unsigned bits = (unsigned)(wd >> kb) & 0xFFu;
            const float4 e4[4] = {ks ? f10 : f00, ks ? f11 : f01,
                                  ks ? f12 : f02, ks ? f13 : f03};
            union { unsigned u[4]; bf16x8 v; } wfr;
            #pragma unroll
            for (int p = 0; p < 4; ++p) {
                const float4 e = e4[p];              // {B0, b0, B1, b1}
                const float m0 = (float)((bits >> (2 * p)) & 1u);
                const float m1 = (float)((bits >> (2 * p + 1)) & 1u);
                const float w0 = fmaxf(rv * e.x, e.y) * m0;
                const float w1 = fmaxf(rv * e.z, e.w) * m1;
                wfr.u[p] = hi_pack2(w0, w1);
            }
            // denominator from the SAME rounded values the PV MFMA consumes
            accd = __builtin_amdgcn_mfma_f32_16x16x32_bf16(wfr.v, ones.v, accd, 0, 0, 0);
            #pragma unroll
            for (int nt = 0; nt < 4; ++nt) {
                const int f = nt * 16 + row;
                const int off = f * 64 + (((ks * 4 + quad) ^ (f & 7)) * 8);
                bf16x8 bh = *(const bf16x8*)&hb[cur][off];
                acc[nt] = __builtin_amdgcn_mfma_f32_16x16x32_bf16(wfr.v, bh, acc[nt], 0, 0, 0);
            }
        }
    }
    #undef STAGE
    float* o = pO + (size_t)blockIdx.y * (GN * 64);
    #pragma unroll
    for (int r = 0; r < 4; ++r) {
        const int grow = i0 + wv * 16 + quad * 4 + r;
        #pragma unroll
        for (int nt = 0; nt < 4; ++nt)
            o[(size_t)grow * 64 + nt * 16 + row] = acc[nt][r];
    }
    // accd: D[i][j] = den_i (cols identical since B==1); C/D row = quad*4+r
    if (row == 0) {
        #pragma unroll
        for (int r = 0; r < 4; ++r)
            pd[blockIdx.y * GN + i0 + wv * 16 + quad * 4 + r] = accd[r];
    }
}

// Fused zred + l2prep, 16 rows/block (256 blocks): combine 2-chunk L1
// partials -> z (LDS) -> h2 = z @ W_out -> row factors + hi-only image.
__global__ __launch_bounds__(256) void mid(const float* __restrict__ pO,
                                           const float* __restrict__ pd,
                                           const float* __restrict__ Wo,
                                           const float* __restrict__ ao,
                                           unsigned short* __restrict__ img2h,
                                           float* __restrict__ rbL,
                                           float2* __restrict__ eb2L) {
    __shared__ __align__(16) float zt[16][68];
    __shared__ float Wl[64 * 57];
    __shared__ float invd[8][16];
    const int tid = threadIdx.x;
    const int i0 = blockIdx.x * 16;
    for (int idx = tid; idx < 64 * 56; idx += 256) {
        int k = idx / 56, c = idx - k * 56;
        Wl[k * 57 + c] = Wo[idx];
    }
    if (tid < 128) {
        int hd = tid >> 4, r = tid & 15;
        invd[hd][r] = 1.f / (pd[(2 * hd) * GN + i0 + r] + pd[(2 * hd + 1) * GN + i0 + r]);
    }
    __syncthreads();
    #pragma unroll
    for (int it = 0; it < 4; ++it) {                 // z fill: 16x64 elems
        int e = it * 256 + tid;
        int r = e >> 6, f = e & 63;
        size_t base = (size_t)(i0 + r) * 64 + f;
        float s = 0.f;
        #pragma unroll
        for (int hd = 0; hd < GNH; ++hd) {
            float o = pO[(size_t)(2 * hd) * (GN * 64) + base] +
                      pO[(size_t)(2 * hd + 1) * (GN * 64) + base];
            float v = o * invd[hd][r];
            s += v > 0.f ? v : FAST_EXP2(v * LOG2E) - 1.f;
        }
        zt[r][f] = s * 0.125f;
    }
    __syncthreads();
    const int rrow = tid >> 4, cseg = (tid & 15) * 4;
    float hreg[4] = {0.f, 0.f, 0.f, 0.f};
    for (int k0 = 0; k0 < 64; k0 += 4) {
        float4 zv = *(const float4*)&zt[rrow][k0];
        #pragma unroll
        for (int c = 0; c < 4; ++c) {
            int col = cseg + c;
            if (col < 56)
                hreg[c] += zv.x * Wl[k0 * 57 + col] + zv.y * Wl[(k0 + 1) * 57 + col] +
                           zv.z * Wl[(k0 + 2) * 57 + col] + zv.w * Wl[(k0 + 3) * 57 + col];
        }
    }
    {   // row factors for L2 attention
        float p1 = 0.f, p2 = 0.f;
        #pragma unroll
        for (int c = 0; c < 4; ++c) {
            int col = cseg + c;
            if (col < 56) {
                p1 += hreg[c] * ao[col];
                p2 += hreg[c] * ao[56 + col];
            }
        }
        p1 += __shfl_xor(p1, 1); p1 += __shfl_xor(p1, 2);
        p1 += __shfl_xor(p1, 4); p1 += __shfl_xor(p1, 8);
        p2 += __shfl_xor(p2, 1); p2 += __shfl_xor(p2, 2);
        p2 += __shfl_xor(p2, 4); p2 += __shfl_xor(p2, 8);
        if ((tid & 15) == 0) {
            rbL[i0 + rrow] = FAST_EXP2(0.8f * p1 * LOG2E);
            float2 e;
            e.x = FAST_EXP2(p2 * LOG2E);
            e.y = FAST_EXP2(0.2f * p2 * LOG2E);
            eb2L[i0 + rrow] = e;
        }
    }
    __syncthreads();
    #pragma unroll
    for (int c = 0; c < 4; ++c) zt[rrow][cseg + c] = (cseg + c < 56) ? hreg[c] : 0.f;
    __syncthreads();
    if (tid < 128) {                                 // img emit: 64 f x 2 c-units
        const int jt = i0 >> 6;
        const int cbase = (i0 & 63) >> 3;
        const int f = tid >> 1, c = cbase + (tid & 1);
        const int lr = (tid & 1) * 8;
        unsigned hp[4];
        #pragma unroll
        for (int pp = 0; pp < 4; ++pp)
            hp[pp] = hi_pack2(zt[lr + 2 * pp][f], zt[lr + 2 * pp + 1][f]);
        size_t base = (size_t)jt * 4096 + f * 64 + ((c ^ (f & 7)) * 8);
        *(uint4*)&img2h[base] = *(uint4*)hp;
    }
}

// combine 16 j-chunk partials, /denom, elu, softmax(56) -> out
__global__ __launch_bounds__(256) void fink2(const float* __restrict__ pO,
                                             const float* __restrict__ pd,
                                             float* __restrict__ out) {
    const int lane = threadIdx.x & 63;
    const int w = threadIdx.x >> 6;
    const int i = blockIdx.x * 4 + w;
    float o = 0.f, d = 0.f;
    #pragma unroll
    for (int c = 0; c < 16; ++c) d += pd[c * GN + i];
    if (lane < 56) {
        #pragma unroll
        for (int c = 0; c < 16; ++c) o += pO[(size_t)c * (GN * 64) + (size_t)i * 64 + lane];
    }
    float v = -1e30f;
    if (lane < 56) {
        float t = o / d;
        v = t > 0.f ? t : expm1f(t);
    }
    float m = v;
    #pragma unroll
    for (int off = 32; off; off >>= 1) m = fmaxf(m, __shfl_down(m, off));
    m = __shfl(m, 0);
    float p = (lane < 56) ? __expf(v - m) : 0.f;
    float s = p;
    #pragma unroll
    for (int off = 32; off; off >>= 1) s += __shfl_down(s, off);
    s = __shfl(s, 0);
    if (lane < 56) out[(size_t)i * 56 + lane] = p / s;
}

extern "C" void kernel_launch(void* const* d_in, const int* in_sizes, int n_in,
                              void* d_out, int out_size, void* d_ws, size_t ws_size,
                              hipStream_t stream) {
    const float* x    = (const float*)d_in[0];
    const int*   adj  = (const int*)d_in[1];
    const float* Ws   = (const float*)d_in[2];
    const float* As   = (const float*)d_in[3];
    const float* Wo   = (const float*)d_in[4];
    const float* ao   = (const float*)d_in[5];
    float* out = (float*)d_out;

    char* ws = (char*)d_ws;
    unsigned long long* adjb = (unsigned long long*)(ws + 0);           // [0, 2097152)
    unsigned short* img1h = (unsigned short*)(ws + 2097152);            // [2097152, 6291456)
    float* pO    = (float*)(ws + 6291456);                              // [6291456, 23068672) 16 slices
    unsigned short* x_hi = (unsigned short*)(ws + 6291456);             // alias pO (pre-gemm only)
    float* pd    = (float*)(ws + 23068672);                             // [23068672, 23330816)
    float* rL    = (float*)(ws + 23330816);                             // [23330816, 23461888)
    float2* ebL  = (float2*)(ws + 23461888);                            // [23461888, 23724032)
    float* rbL   = (float*)(ws + 23724032);                             // [23724032, 23740416)
    float2* eb2L = (float2*)(ws + 23740416);                            // [23740416, 23773184)
    unsigned short* img2h = (unsigned short*)(ws + 23773184);           // [23773184, 24297472)
    unsigned short* WT_hi = (unsigned short*)(ws + 24297472);           // [24297472, 24821760)
    // total ~24.82 MB, no overlaps

    prep<<<17472, 256, 0, stream>>>(adj, x, Ws, adjb, x_hi, WT_hi);
    gemm_fused<<<dim3(8, 64), 256, 0, stream>>>(x_hi, WT_hi, As, img1h, rL, ebL);
    attn10<2><<<dim3(64, 16), 256, 0, stream>>>(img1h, rL, ebL, adjb, pO, pd);
    mid<<<256, 256, 0, stream>>>(pO, pd, Wo, ao, img2h, rbL, eb2L);
    attn10<16><<<dim3(64, 16), 256, 0, stream>>>(img2h, rbL, eb2L, adjb, pO, pd);
    fink2<<<1024, 256, 0, stream>>>(pO, pd, out);
}

// Round 5
// 205.648 us; speedup vs baseline: 1.0478x; 1.0082x over previous
//
#include <hip/hip_runtime.h>
#include <hip/hip_bf16.h>
#include <math.h>

// GAT forward, N=4096, nfeat=512, nhid=64, nheads=8, nout=56, f32 in/out.
// R20 vs R19 (R19: 207.3us; attn-L1 67.8us). Cross-round data: wall/tile
// ~4900-5460 cyc across R15/R18/R19 while VALU insts/tile varied 317-410
// -> attn is NOT VALU-issue-bound; ~38% of cycles are all-wave stalls that
// track the BARRIER COUNT (1 per j-tile: vmcnt0 drain + 4-block skew).
//  - attn10: TWO j-tiles per barrier phase. hb = [2 bufs][2 tiles] = 32 KB
//    (4 blk/CU preserved: LDS limit 160/32=5). Barriers 32->16 (L1), 4->2
//    (L2). STAGE2 stages 2 contiguous tiles (8 KB) per phase; scalar
//    prefetch rotates per tile as in R19. Same math, same order -> bit-
//    identical output vs R19.
//  - everything outstanding at each barrier is still consumed right after
//    it (stage flight = full phase ~2x compute; scalars ~1 tile) -> the
//    vmcnt(0) drain wastes nothing.
// prep / gemm_fused / mid / fink2 / workspace byte-identical to R19.

#define GN 4096
#define GNH 8
#define LOG2E 1.4426950408889634f

typedef __bf16 bf16x8 __attribute__((ext_vector_type(8)));
typedef float f32x4 __attribute__((ext_vector_type(4)));

#if defined(__has_builtin)
#if __has_builtin(__builtin_amdgcn_exp2f)
#define FAST_EXP2(x) __builtin_amdgcn_exp2f(x)
#endif
#if __has_builtin(__builtin_amdgcn_perm)
#define FAST_PERM(a, b, s) __builtin_amdgcn_perm((a), (b), (s))
#endif
#endif
#ifndef FAST_EXP2
#define FAST_EXP2(x) __expf((x)*0.6931471805599453f)
#endif
#ifndef FAST_PERM
__device__ inline unsigned FAST_PERM(unsigned a, unsigned b, unsigned) {
    return (a & 0xFFFF0000u) | (b >> 16);
}
#endif

// round-half-up hi only, packed pair: low 16 = v0's bf16, high 16 = v1's
__device__ inline unsigned hi_pack2(float w0, float w1) {
    unsigned u0 = __float_as_uint(w0) + 0x8000u;
    unsigned u1 = __float_as_uint(w1) + 0x8000u;
    return FAST_PERM(u1, u0, 0x07060302u);
}

// Fused prep:
//  [0,16384)      pack_adj  (bitmask)
//  [16384,17408)  conv_x    -> swizzled x image (hi only), tiles [itile*8+kt]
//  [17408,17472)  conv_wt   -> swizzled W^T image (hi only), tiles [head*8+kt]
// Image unit (m, c) at shorts offset m*64 + ((c^(m&7))*8), elems k = c*8+q.
__global__ __launch_bounds__(256) void prep(const int* __restrict__ adj,
                                            const float* __restrict__ x,
                                            const float* __restrict__ Ws,
                                            unsigned long long* __restrict__ adjb,
                                            unsigned short* __restrict__ xh,
                                            unsigned short* __restrict__ wth) {
    const int b = blockIdx.x;
    const int tid = threadIdx.x;
    if (b < 16384) {
        const int wv = tid >> 6, lane = tid & 63;
        const size_t ebase = ((size_t)b * 4 + wv) * 256;
        unsigned long long m[4];
        #pragma unroll
        for (int e = 0; e < 4; ++e)
            m[e] = __ballot(adj[ebase + e * 64 + lane] > 0);
        if (lane == 0) {
            #pragma unroll
            for (int e = 0; e < 4; ++e) adjb[(ebase >> 6) + e] = m[e];
        }
    } else if (b < 17408) {
        int gid = (b - 16384) * 256 + tid;           // over 4096 rows x 64 units
        int i = gid >> 6, c64 = gid & 63;
        const float* xp = x + (size_t)i * 512 + c64 * 8;
        float4 a = *(const float4*)xp;
        float4 v = *(const float4*)(xp + 4);
        unsigned hp[4];
        hp[0] = hi_pack2(a.x, a.y);
        hp[1] = hi_pack2(a.z, a.w);
        hp[2] = hi_pack2(v.x, v.y);
        hp[3] = hi_pack2(v.z, v.w);
        int il = i & 63, kt = c64 >> 3, c = c64 & 7;
        size_t base = ((size_t)(i >> 6) * 8 + kt) * 4096 + il * 64 + ((c ^ (il & 7)) * 8);
        *(uint4*)&xh[base] = *(uint4*)hp;
    } else {
        __shared__ float t[64][65];
        int b2 = b - 17408;                          // head*8 + kt
        int head = b2 >> 3, k0 = (b2 & 7) * 64;
        #pragma unroll
        for (int it = 0; it < 4; ++it) {
            int e = (tid + it * 256) * 4;            // over 64k x 64f
            int kl = e >> 6, f4 = e & 63;
            float4 v = *(const float4*)&Ws[((size_t)head * 512 + k0 + kl) * 64 + f4];
            t[f4 + 0][kl] = v.x; t[f4 + 1][kl] = v.y;
            t[f4 + 2][kl] = v.z; t[f4 + 3][kl] = v.w;
        }
        __syncthreads();
        int f = tid >> 2;
        #pragma unroll
        for (int p = 0; p < 2; ++p) {
            int c = (tid & 3) * 2 + p;
            unsigned hp[4];
            #pragma unroll
            for (int pp = 0; pp < 4; ++pp)
                hp[pp] = hi_pack2(t[f][c * 8 + 2 * pp], t[f][c * 8 + 2 * pp + 1]);
            size_t base = (size_t)b2 * 4096 + f * 64 + ((c ^ (f & 7)) * 8);
            *(uint4*)&wth[base] = *(uint4*)hp;
        }
    }
}

// h = x_hi @ W_hi (single bf16 product), m97-style staging, 4 blk/CU.
// Epilogue emits hi-only swizzled h image + per-row softmax factors:
// rL = exp(.8*s1), ebL = {exp(s2), exp(.2*s2)}. grid (8 heads, 64 itiles).
__global__ __launch_bounds__(256) void gemm_fused(const unsigned short* __restrict__ xh,
                                                  const unsigned short* __restrict__ wth,
                                                  const float* __restrict__ As,
                                                  unsigned short* __restrict__ imgh,
                                                  float* __restrict__ rL,
                                                  float2* __restrict__ ebL) {
    __shared__ __align__(16) unsigned short lds[2][2][4096];  // 32 KB: [buf][x,w]
    const int tid = threadIdx.x;
    const int head = blockIdx.x;
    const int itile = blockIdx.y;
    const int i0 = itile * 64;
    const unsigned short* srcs[2] = {xh + (size_t)itile * 8 * 4096,
                                     wth + (size_t)head * 8 * 4096};
    const int lane = tid & 63, wv_ = tid >> 6;
    const int mi = (wv_ & 1) * 32, fi = (wv_ >> 1) * 32;
    const int row = lane & 15, quad = lane >> 4;
    f32x4 acc[2][2] = {};

    #define GSTAGE(buf, kt)                                                                \
        do {                                                                               \
            _Pragma("unroll")                                                              \
            for (int q_ = 0; q_ < 2; ++q_) {                                               \
                const unsigned short* s_ = srcs[q_] + (size_t)(kt) * 4096;                 \
                _Pragma("unroll")                                                          \
                for (int c_ = 0; c_ < 2; ++c_)                                             \
                    __builtin_amdgcn_global_load_lds(                                      \
                        (const __attribute__((address_space(1))) unsigned int*)(s_ + c_ * 2048 + tid * 8), \
                        (__attribute__((address_space(3))) unsigned int*)&lds[buf][q_][c_ * 2048 + tid * 8], \
                        16, 0, 0);                                                         \
            }                                                                              \
        } while (0)

    GSTAGE(0, 0);
    for (int kt = 0; kt < 8; ++kt) {
        __syncthreads();                             // drains loads into buf cur
        const int cur = kt & 1;
        if (kt + 1 < 8) GSTAGE(cur ^ 1, kt + 1);
        #pragma unroll
        for (int ks = 0; ks < 2; ++ks) {
            bf16x8 ah[2], bh[2];
            #pragma unroll
            for (int t = 0; t < 2; ++t) {
                const int m_ = mi + t * 16 + row;
                const int offa = m_ * 64 + (((ks * 4 + quad) ^ (m_ & 7)) * 8);
                ah[t] = *(const bf16x8*)&lds[cur][0][offa];
                const int f_ = fi + t * 16 + row;
                const int offb = f_ * 64 + (((ks * 4 + quad) ^ (f_ & 7)) * 8);
                bh[t] = *(const bf16x8*)&lds[cur][1][offb];
            }
            #pragma unroll
            for (int mt = 0; mt < 2; ++mt)
                #pragma unroll
                for (int nt = 0; nt < 2; ++nt)
                    acc[mt][nt] = __builtin_amdgcn_mfma_f32_16x16x32_bf16(ah[mt], bh[nt], acc[mt][nt], 0, 0, 0);
        }
    }
    #undef GSTAGE
    // ---- fused epilogue ----
    __syncthreads();
    float* ht = (float*)&lds[0][0][0];               // 64 x 68 f32 (17.4 KB <= 32 KB)
    #pragma unroll
    for (int mt = 0; mt < 2; ++mt)
        #pragma unroll
        for (int nt = 0; nt < 2; ++nt)
            #pragma unroll
            for (int r = 0; r < 4; ++r)
                ht[(mi + mt * 16 + quad * 4 + r) * 68 + fi + nt * 16 + row] = acc[mt][nt][r];
    __syncthreads();
    {   // s1/s2 -> row factors: thread t -> row t>>2, seg (t&3)*16
        const int rrow = tid >> 2, seg = (tid & 3) * 16;
        const float* ah = As + head * 128;
        float p1 = 0.f, p2 = 0.f;
        #pragma unroll
        for (int c = 0; c < 16; ++c) {
            float v = ht[rrow * 68 + seg + c];
            p1 += v * ah[seg + c];
            p2 += v * ah[64 + seg + c];
        }
        p1 += __shfl_xor(p1, 1); p1 += __shfl_xor(p1, 2);
        p2 += __shfl_xor(p2, 1); p2 += __shfl_xor(p2, 2);
        if ((tid & 3) == 0) {
            const int gi = i0 + rrow;
            rL[head * GN + gi] = FAST_EXP2(0.8f * p1 * LOG2E);
            float2 e;
            e.x = FAST_EXP2(p2 * LOG2E);
            e.y = FAST_EXP2(0.2f * p2 * LOG2E);
            ebL[head * GN + gi] = e;
        }
    }
    {   // swizzled image emit (hi only)
        const int f = tid >> 2;
        size_t base = ((size_t)head * 64 + itile) * 4096 + (size_t)f * 64;
        #pragma unroll
        for (int p = 0; p < 2; ++p) {
            int c = (tid & 3) * 2 + p;
            unsigned hp[4];
            #pragma unroll
            for (int pp = 0; pp < 4; ++pp)
                hp[pp] = hi_pack2(ht[(c * 8 + 2 * pp) * 68 + f], ht[(c * 8 + 2 * pp + 1) * 68 + f]);
            int off = (c ^ (f & 7)) * 8;
            *(uint4*)&imgh[base + off] = *(uint4*)hp;
        }
    }
}

// Fused masked-softmax attention, MULTIPLICATIVE weights:
// w'_ij = max(r_i*B_j, b_j) * adj  -- no transcendentals in the loop.
// R20: TWO j-tiles per barrier phase (hb = 2 bufs x 2 tiles = 32 KB), so
// barrier count halves (L1 32->16, L2 4->2). Per-tile scalar prefetch
// rotation kept from R19. den = ones-column MFMA on the SAME rounded bf16
// weights. 256 thr = 4 waves x 16 rows, nt=4.
// grid (64 i-tiles, GNH*NCHUNK or NCHUNK).
template <int NCHUNK>
__global__ __launch_bounds__(256, 4) void attn10(const unsigned short* __restrict__ imgh,
                                                 const float* __restrict__ rg,
                                                 const float2* __restrict__ ebg,
                                                 const unsigned long long* __restrict__ adjb,
                                                 float* __restrict__ pO,
                                                 float* __restrict__ pd) {
    __shared__ __align__(16) unsigned short hb[2][8192];   // [buf][2 tiles, swizzled]
    const int tid = threadIdx.x;
    const int lane = tid & 63, wv = tid >> 6;
    const int row = lane & 15, quad = lane >> 4;
    const int head = blockIdx.y / NCHUNK;
    const int chunk = blockIdx.y % NCHUNK;
    const int i0 = blockIdx.x * 64;
    const int jb = chunk * (GN / NCHUNK);
    const int njt = (GN / NCHUNK) / 64;
    const int njp = njt >> 1;                        // 2 tiles per phase
    const int jt0 = jb >> 6;
    const unsigned short* ih = imgh + (size_t)head * (64 * GN);
    const float2* ebh = ebg + (size_t)head * GN;
    const int gr = i0 + wv * 16 + row;
    const float rv = rg[head * GN + gr];
    const unsigned long long* adjr = adjb + (size_t)gr * 64 + jt0;

    f32x4 acc[4] = {};
    f32x4 accd = {};
    union { unsigned u[4]; bf16x8 v; } ones;
    #pragma unroll
    for (int q = 0; q < 4; ++q) ones.u[q] = 0x3F803F80u;   // bf16 1.0 x8

    // stage tiles T and T+1 (contiguous 16 KB in imgh) into hb[buf]
    #define STAGE2(buf, T)                                                                 \
        do {                                                                               \
            const unsigned short* gh_ = ih + (size_t)(T) * 4096;                           \
            _Pragma("unroll")                                                              \
            for (int c_ = 0; c_ < 4; ++c_)                                                 \
                __builtin_amdgcn_global_load_lds(                                          \
                    (const __attribute__((address_space(1))) unsigned int*)(gh_ + c_ * 2048 + tid * 8), \
                    (__attribute__((address_space(3))) unsigned int*)&hb[buf][c_ * 2048 + tid * 8],     \
                    16, 0, 0);                                                             \
        } while (0)

    // one j-tile's weight-pack + 5 MFMA against hb[cur] half `half`
    #define CTILE(cur, half, WD, F00, F01, F02, F03, F10, F11, F12, F13)                   \
        do {                                                                               \
            _Pragma("unroll")                                                              \
            for (int ks = 0; ks < 2; ++ks) {                                               \
                const int kb = ks * 32 + quad * 8;                                         \
                const unsigned bits = (unsigned)((WD) >> kb) & 0xFFu;                      \
                const float4 e4[4] = {ks ? F10 : F00, ks ? F11 : F01,                      \
                                      ks ? F12 : F02, ks ? F13 : F03};                     \
                union { unsigned u[4]; bf16x8 v; } wfr;                                    \
                _Pragma("unroll")                                                          \
                for (int p = 0; p < 4; ++p) {                                              \
                    const float4 e = e4[p];          /* {B0, b0, B1, b1} */                \
                    const float m0 = (float)((bits >> (2 * p)) & 1u);                      \
                    const float m1 = (float)((bits >> (2 * p + 1)) & 1u);                  \
                    const float w0 = fmaxf(rv * e.x, e.y) * m0;                            \
                    const float w1 = fmaxf(rv * e.z, e.w) * m1;                            \
                    wfr.u[p] = hi_pack2(w0, w1);                                           \
                }                                                                          \
                accd = __builtin_amdgcn_mfma_f32_16x16x32_bf16(wfr.v, ones.v, accd, 0, 0, 0); \
                _Pragma("unroll")                                                          \
                for (int nt = 0; nt < 4; ++nt) {                                           \
                    const int f = nt * 16 + row;                                           \
                    const int off = (half) * 4096 + f * 64 + (((ks * 4 + quad) ^ (f & 7)) * 8); \
                    bf16x8 bh = *(const bf16x8*)&hb[cur][off];                             \
                    acc[nt] = __builtin_amdgcn_mfma_f32_16x16x32_bf16(wfr.v, bh, acc[nt], 0, 0, 0); \
                }                                                                          \
            }                                                                              \
        } while (0)

    STAGE2(0, jt0);
    // ---- prologue prefetch of tile 0 scalars (covered by first barrier) ----
    const float2* ebp = ebh + jb + quad * 8;
    unsigned long long wdn = adjr[0];
    float4 n00 = *(const float4*)(ebp + 0);
    float4 n01 = *(const float4*)(ebp + 2);
    float4 n02 = *(const float4*)(ebp + 4);
    float4 n03 = *(const float4*)(ebp + 6);
    float4 n10 = *(const float4*)(ebp + 32);
    float4 n11 = *(const float4*)(ebp + 34);
    float4 n12 = *(const float4*)(ebp + 36);
    float4 n13 = *(const float4*)(ebp + 38);

    for (int ph = 0; ph < njp; ++ph) {
        __syncthreads();                             // drains stage+scalars for this phase
        const int cur = ph & 1;
        if (ph + 1 < njp) STAGE2(cur ^ 1, jt0 + 2 * (ph + 1));
        // ---- tile A = 2*ph ----
        {
            const unsigned long long wd = wdn;
            const float4 f00 = n00, f01 = n01, f02 = n02, f03 = n03;
            const float4 f10 = n10, f11 = n11, f12 = n12, f13 = n13;
            {   // prefetch tile 2*ph+1 scalars (always exists: 2ph+1 <= njt-1)
                const int tn = 2 * ph + 1;
                wdn = adjr[tn];
                const float2* ebn = ebp + tn * 64;
                n00 = *(const float4*)(ebn + 0);
                n01 = *(const float4*)(ebn + 2);
                n02 = *(const float4*)(ebn + 4);
                n03 = *(const float4*)(ebn + 6);
                n10 = *(const float4*)(ebn + 32);
                n11 = *(const float4*)(ebn + 34);
                n12 = *(const float4*)(ebn + 36);
                n13 = *(const float4*)(ebn + 38);
            }
            CTILE(cur, 0, wd, f00, f01, f02, f03, f10, f11, f12, f13);
        }
        // ---- tile B = 2*ph+1 ----
        {
            const unsigned long long wd = wdn;
            const float4 f00 = n00, f01 = n01, f02 = n02, f03 = n03;
            const float4 f10 = n10, f11 = n11, f12 = n12, f13 = n13;
            if (ph + 1 < njp) {                      // prefetch first tile of next phase
                const int tn = 2 * ph + 2;
                wdn = adjr[tn];
                const float2* ebn = ebp + tn * 64;
                n00 = *(const float4*)(ebn + 0);
                n01 = *(const float4*)(ebn + 2);
                n02 = *(const float4*)(ebn + 4);
                n03 = *(const float4*)(ebn + 6);
                n10 = *(const float4*)(ebn + 32);
                n11 = *(const float4*)(ebn + 34);
                n12 = *(const float4*)(ebn + 36);
                n13 = *(const float4*)(ebn + 38);
            }
            CTILE(cur, 1, wd, f00, f01, f02, f03, f10, f11, f12, f13);
        }
    }
    #undef STAGE2
    #undef CTILE
    float* o = pO + (size_t)blockIdx.y * (GN * 64);
    #pragma unroll
    for (int r = 0; r < 4; ++r) {
        const int grow = i0 + wv * 16 + quad * 4 + r;
        #pragma unroll
        for (int nt = 0; nt < 4; ++nt)
            o[(size_t)grow * 64 + nt * 16 + row] = acc[nt][r];
    }
    // accd: D[i][j] = den_i (cols identical since B==1); C/D row = quad*4+r
    if (row == 0) {
        #pragma unroll
        for (int r = 0; r < 4; ++r)
            pd[blockIdx.y * GN + i0 + wv * 16 + quad * 4 + r] = accd[r];
    }
}

// Fused zred + l2prep, 16 rows/block (256 blocks): combine 2-chunk L1
// partials -> z (LDS) -> h2 = z @ W_out -> row factors + hi-only image.
__global__ __launch_bounds__(256) void mid(const float* __restrict__ pO,
                                           const float* __restrict__ pd,
                                           const float* __restrict__ Wo,
                                           const float* __restrict__ ao,
                                           unsigned short* __restrict__ img2h,
                                           float* __restrict__ rbL,
                                           float2* __restrict__ eb2L) {
    __shared__ __align__(16) float zt[16][68];
    __shared__ float Wl[64 * 57];
    __shared__ float invd[8][16];
    const int tid = threadIdx.x;
    const int i0 = blockIdx.x * 16;
    for (int idx = tid; idx < 64 * 56; idx += 256) {
        int k = idx / 56, c = idx - k * 56;
        Wl[k * 57 + c] = Wo[idx];
    }
    if (tid < 128) {
        int hd = tid >> 4, r = tid & 15;
        invd[hd][r] = 1.f / (pd[(2 * hd) * GN + i0 + r] + pd[(2 * hd + 1) * GN + i0 + r]);
    }
    __syncthreads();
    #pragma unroll
    for (int it = 0; it < 4; ++it) {                 // z fill: 16x64 elems
        int e = it * 256 + tid;
        int r = e >> 6, f = e & 63;
        size_t base = (size_t)(i0 + r) * 64 + f;
        float s = 0.f;
        #pragma unroll
        for (int hd = 0; hd < GNH; ++hd) {
            float o = pO[(size_t)(2 * hd) * (GN * 64) + base] +
                      pO[(size_t)(2 * hd + 1) * (GN * 64) + base];
            float v = o * invd[hd][r];
            s += v > 0.f ? v : FAST_EXP2(v * LOG2E) - 1.f;
        }
        zt[r][f] = s * 0.125f;
    }
    __syncthreads();
    const int rrow = tid >> 4, cseg = (tid & 15) * 4;
    float hreg[4] = {0.f, 0.f, 0.f, 0.f};
    for (int k0 = 0; k0 < 64; k0 += 4) {
        float4 zv = *(const float4*)&zt[rrow][k0];
        #pragma unroll
        for (int c = 0; c < 4; ++c) {
            int col = cseg + c;
            if (col < 56)
                hreg[c] += zv.x * Wl[k0 * 57 + col] + zv.y * Wl[(k0 + 1) * 57 + col] +
                           zv.z * Wl[(k0 + 2) * 57 + col] + zv.w * Wl[(k0 + 3) * 57 + col];
        }
    }
    {   // row factors for L2 attention
        float p1 = 0.f, p2 = 0.f;
        #pragma unroll
        for (int c = 0; c < 4; ++c) {
            int col = cseg + c;
            if (col < 56) {
                p1 += hreg[c] * ao[col];
                p2 += hreg[c] * ao[56 + col];
            }
        }
        p1 += __shfl_xor(p1, 1); p1 += __shfl_xor(p1, 2);
        p1 += __shfl_xor(p1, 4); p1 += __shfl_xor(p1, 8);
        p2 += __shfl_xor(p2, 1); p2 += __shfl_xor(p2, 2);
        p2 += __shfl_xor(p2, 4); p2 += __shfl_xor(p2, 8);
        if ((tid & 15) == 0) {
            rbL[i0 + rrow] = FAST_EXP2(0.8f * p1 * LOG2E);
            float2 e;
            e.x = FAST_EXP2(p2 * LOG2E);
            e.y = FAST_EXP2(0.2f * p2 * LOG2E);
            eb2L[i0 + rrow] = e;
        }
    }
    __syncthreads();
    #pragma unroll
    for (int c = 0; c < 4; ++c) zt[rrow][cseg + c] = (cseg + c < 56) ? hreg[c] : 0.f;
    __syncthreads();
    if (tid < 128) {                                 // img emit: 64 f x 2 c-units
        const int jt = i0 >> 6;
        const int cbase = (i0 & 63) >> 3;
        const int f = tid >> 1, c = cbase + (tid & 1);
        const int lr = (tid & 1) * 8;
        unsigned hp[4];
        #pragma unroll
        for (int pp = 0; pp < 4; ++pp)
            hp[pp] = hi_pack2(zt[lr + 2 * pp][f], zt[lr + 2 * pp + 1][f]);
        size_t base = (size_t)jt * 4096 + f * 64 + ((c ^ (f & 7)) * 8);
        *(uint4*)&img2h[base] = *(uint4*)hp;
    }
}

// combine 16 j-chunk partials, /denom, elu, softmax(56) -> out
__global__ __launch_bounds__(256) void fink2(const float* __restrict__ pO,
                                             const float* __restrict__ pd,
                                             float* __restrict__ out) {
    const int lane = threadIdx.x & 63;
    const int w = threadIdx.x >> 6;
    const int i = blockIdx.x * 4 + w;
    float o = 0.f, d = 0.f;
    #pragma unroll
    for (int c = 0; c < 16; ++c) d += pd[c * GN + i];
    if (lane < 56) {
        #pragma unroll
        for (int c = 0; c < 16; ++c) o += pO[(size_t)c * (GN * 64) + (size_t)i * 64 + lane];
    }
    float v = -1e30f;
    if (lane < 56) {
        float t = o / d;
        v = t > 0.f ? t : expm1f(t);
    }
    float m = v;
    #pragma unroll
    for (int off = 32; off; off >>= 1) m = fmaxf(m, __shfl_down(m, off));
    m = __shfl(m, 0);
    float p = (lane < 56) ? __expf(v - m) : 0.f;
    float s = p;
    #pragma unroll
    for (int off = 32; off; off >>= 1) s += __shfl_down(s, off);
    s = __shfl(s, 0);
    if (lane < 56) out[(size_t)i * 56 + lane] = p / s;
}

extern "C" void kernel_launch(void* const* d_in, const int* in_sizes, int n_in,
                              void* d_out, int out_size, void* d_ws, size_t ws_size,
                              hipStream_t stream) {
    const float* x    = (const float*)d_in[0];
    const int*   adj  = (const int*)d_in[1];
    const float* Ws   = (const float*)d_in[2];
    const float* As   = (const float*)d_in[3];
    const float* Wo   = (const float*)d_in[4];
    const float* ao   = (const float*)d_in[5];
    float* out = (float*)d_out;

    char* ws = (char*)d_ws;
    unsigned long long* adjb = (unsigned long long*)(ws + 0);           // [0, 2097152)
    unsigned short* img1h = (unsigned short*)(ws + 2097152);            // [2097152, 6291456)
    float* pO    = (float*)(ws + 6291456);                              // [6291456, 23068672) 16 slices
    unsigned short* x_hi = (unsigned short*)(ws + 6291456);             // alias pO (pre-gemm only)
    float* pd    = (float*)(ws + 23068672);                             // [23068672, 23330816)
    float* rL    = (float*)(ws + 23330816);                             // [23330816, 23461888)
    float2* ebL  = (float2*)(ws + 23461888);                            // [23461888, 23724032)
    float* rbL   = (float*)(ws + 23724032);                             // [23724032, 23740416)
    float2* eb2L = (float2*)(ws + 23740416);                            // [23740416, 23773184)
    unsigned short* img2h = (unsigned short*)(ws + 23773184);           // [23773184, 24297472)
    unsigned short* WT_hi = (unsigned short*)(ws + 24297472);           // [24297472, 24821760)
    // total ~24.82 MB, no overlaps

    prep<<<17472, 256, 0, stream>>>(adj, x, Ws, adjb, x_hi, WT_hi);
    gemm_fused<<<dim3(8, 64), 256, 0, stream>>>(x_hi, WT_hi, As, img1h, rL, ebL);
    attn10<2><<<dim3(64, 16), 256, 0, stream>>>(img1h, rL, ebL, adjb, pO, pd);
    mid<<<256, 256, 0, stream>>>(pO, pd, Wo, ao, img2h, rbL, eb2L);
    attn10<16><<<dim3(64, 16), 256, 0, stream>>>(img2h, rbL, eb2L, adjb, pO, pd);
    fink2<<<1024, 256, 0, stream>>>(pO, pd, out);
}